// Round 2
// baseline (1991.860 us; speedup 1.0000x reference)
//
#include <hip/hip_runtime.h>
#include <hip/hip_bf16.h>
#include <stdint.h>

// MultiHeadAttention fwd: B=32 L=1024 D=256 H=4 DH=128.
// Outputs (concatenated in d_out): out [32,1024,256] f32, attn [32,4,1024,1024] f32.
// R1: attn_kernel rewritten as barrier-free per-wave flash-style two-pass:
//  - wave = 16 q-rows x full 1024 k; 4 waves/block; no __syncthreads anywhere.
//  - pass1: plain-bf16 QK^T -> rowsum(exp) (sum needs only ~1e-3 rel accuracy).
//  - pass2: 3-term split-bf16 QK^T -> normalized attn (nontemporal stores) ->
//    P packed bf16 via 1.25KB per-wave LDS scratch -> PV MFMA -> ctx.
//  - d_ws layout (bf16): Qh|Ql|Kh|Kl|Vt|ctx, 6 x 16777216 elems = 201 MB.

#define B_  32
#define L_  1024
#define D_  256
#define H_  4
#define DH_ 128

typedef __attribute__((ext_vector_type(8))) short bf16x8;
typedef __attribute__((ext_vector_type(4))) float f32x4;

#define MFMA16(a, b, c) __builtin_amdgcn_mfma_f32_16x16x32_bf16((a), (b), (c), 0, 0, 0)

__device__ __forceinline__ uint16_t f2bf(float x) {
  uint32_t u = __float_as_uint(x);
  u += 0x7FFFu + ((u >> 16) & 1u);   // RNE
  return (uint16_t)(u >> 16);
}
__device__ __forceinline__ float bf2f(uint16_t h) {
  return __uint_as_float((uint32_t)h << 16);
}
__device__ __forceinline__ uint32_t pk2(float a, float b) {
  return (uint32_t)f2bf(a) | ((uint32_t)f2bf(b) << 16);
}

// ---------------------------------------------------------------------------
// QKV projection (unchanged from R0 — verified correct).
// ---------------------------------------------------------------------------
__global__ __launch_bounds__(256) void proj_kernel(
    const float* __restrict__ Xq, const float* __restrict__ Xk, const float* __restrict__ Xv,
    const float* __restrict__ Wq, const float* __restrict__ bq,
    const float* __restrict__ Wk, const float* __restrict__ bk,
    const float* __restrict__ Wv, const float* __restrict__ bv,
    uint16_t* __restrict__ Qh, uint16_t* __restrict__ Ql,
    uint16_t* __restrict__ Kh, uint16_t* __restrict__ Kl,
    uint16_t* __restrict__ Vt)
{
  const int mode = blockIdx.z;
  const float* X    = (mode == 0) ? Xq : (mode == 1) ? Xk : Xv;
  const float* W    = (mode == 0) ? Wq : (mode == 1) ? Wk : Wv;
  const float* bias = (mode == 0) ? bq : (mode == 1) ? bk : bv;

  __shared__ __align__(16) uint8_t smem[65536];  // Xh|Xl|Wh|Wl, 16KB each
  uint8_t* XhS = smem;
  uint8_t* XlS = smem + 16384;
  uint8_t* WhS = smem + 32768;
  uint8_t* WlS = smem + 49152;

  const int t  = threadIdx.x;
  const int m0 = blockIdx.x * 64;
  const int n0 = blockIdx.y * 64;
  const int w = t >> 6, l = t & 63, lg = l >> 4, l16 = l & 15;
  const int wm = (w >> 1) * 32, wn = (w & 1) * 32;

  f32x4 acc[2][2] = {};

  for (int kc = 0; kc < 2; ++kc) {
    __syncthreads();
    #pragma unroll
    for (int i = 0; i < 8; ++i) {
      int f = i * 256 + t;
      int row = f >> 5, c4 = f & 31;
      f32x4 v = *reinterpret_cast<const f32x4*>(X + (size_t)(m0 + row) * 256 + kc * 128 + c4 * 4);
      uint32_t byte = (((uint32_t)row * 256 + (uint32_t)c4 * 8)) ^ ((uint32_t)(row & 7) << 4);
      uint16_t h0 = f2bf(v[0]), h1 = f2bf(v[1]), h2 = f2bf(v[2]), h3 = f2bf(v[3]);
      *reinterpret_cast<uint2*>(XhS + byte) =
          make_uint2((uint32_t)h0 | ((uint32_t)h1 << 16), (uint32_t)h2 | ((uint32_t)h3 << 16));
      if (mode < 2) {
        uint16_t e0 = f2bf(v[0] - bf2f(h0)), e1 = f2bf(v[1] - bf2f(h1));
        uint16_t e2 = f2bf(v[2] - bf2f(h2)), e3 = f2bf(v[3] - bf2f(h3));
        *reinterpret_cast<uint2*>(XlS + byte) =
            make_uint2((uint32_t)e0 | ((uint32_t)e1 << 16), (uint32_t)e2 | ((uint32_t)e3 << 16));
      }
    }
    #pragma unroll
    for (int i = 0; i < 8; ++i) {
      int f = i * 256 + t;
      int row = f >> 5, c4 = f & 31;
      f32x4 v = *reinterpret_cast<const f32x4*>(W + (size_t)(n0 + row) * 256 + kc * 128 + c4 * 4);
      uint32_t byte = (((uint32_t)row * 256 + (uint32_t)c4 * 8)) ^ ((uint32_t)(row & 7) << 4);
      uint16_t h0 = f2bf(v[0]), h1 = f2bf(v[1]), h2 = f2bf(v[2]), h3 = f2bf(v[3]);
      *reinterpret_cast<uint2*>(WhS + byte) =
          make_uint2((uint32_t)h0 | ((uint32_t)h1 << 16), (uint32_t)h2 | ((uint32_t)h3 << 16));
      if (mode < 2) {
        uint16_t e0 = f2bf(v[0] - bf2f(h0)), e1 = f2bf(v[1] - bf2f(h1));
        uint16_t e2 = f2bf(v[2] - bf2f(h2)), e3 = f2bf(v[3] - bf2f(h3));
        *reinterpret_cast<uint2*>(WlS + byte) =
            make_uint2((uint32_t)e0 | ((uint32_t)e1 << 16), (uint32_t)e2 | ((uint32_t)e3 << 16));
      }
    }
    __syncthreads();

    #pragma unroll
    for (int ks = 0; ks < 4; ++ks) {
      bf16x8 ah[2], al[2], bh[2], bl[2];
      #pragma unroll
      for (int mt = 0; mt < 2; ++mt) {
        int row = wm + mt * 16 + l16;
        uint32_t byte = ((uint32_t)row * 256 + (uint32_t)(ks * 64 + lg * 16)) ^ ((uint32_t)(row & 7) << 4);
        ah[mt] = *reinterpret_cast<bf16x8*>(XhS + byte);
        if (mode < 2) al[mt] = *reinterpret_cast<bf16x8*>(XlS + byte);
      }
      #pragma unroll
      for (int nt = 0; nt < 2; ++nt) {
        int row = wn + nt * 16 + l16;
        uint32_t byte = ((uint32_t)row * 256 + (uint32_t)(ks * 64 + lg * 16)) ^ ((uint32_t)(row & 7) << 4);
        bh[nt] = *reinterpret_cast<bf16x8*>(WhS + byte);
        if (mode < 2) bl[nt] = *reinterpret_cast<bf16x8*>(WlS + byte);
      }
      #pragma unroll
      for (int mt = 0; mt < 2; ++mt)
        #pragma unroll
        for (int nt = 0; nt < 2; ++nt) {
          acc[mt][nt] = MFMA16(ah[mt], bh[nt], acc[mt][nt]);
          if (mode < 2) {
            acc[mt][nt] = MFMA16(ah[mt], bl[nt], acc[mt][nt]);
            acc[mt][nt] = MFMA16(al[mt], bh[nt], acc[mt][nt]);
          }
        }
    }
  }

  #pragma unroll
  for (int nt = 0; nt < 2; ++nt) {
    int n = n0 + wn + nt * 16 + l16;
    float bias_v = bias[n];
    int hh = n >> 7, d = n & 127;
    #pragma unroll
    for (int mt = 0; mt < 2; ++mt) {
      #pragma unroll
      for (int r = 0; r < 4; ++r) {
        int m = m0 + wm + mt * 16 + lg * 4 + r;
        int bb = m >> 10, lq = m & 1023;
        float val = acc[mt][nt][r] + bias_v;
        if (mode == 2) {
          Vt[((size_t)(bb * 4 + hh) * 128 + d) * 1024 + lq] = f2bf(val);
        } else {
          size_t idx = ((size_t)(bb * 4 + hh) * 1024 + lq) * 128 + d;
          uint16_t hv = f2bf(val);
          uint16_t lv = f2bf(val - bf2f(hv));
          if (mode == 0) { Qh[idx] = hv; Ql[idx] = lv; }
          else           { Kh[idx] = hv; Kl[idx] = lv; }
        }
      }
    }
  }
}

// ---------------------------------------------------------------------------
// Attention, barrier-free two-pass. Block = 4 independent waves; wave = 16
// q-rows x full k. Swapped QK^T: mfma(A=K_rows, B=Q) -> C[k][q=l16].
// pass1: plain bf16 -> rowsum(exp). pass2: split-bf16 -> attn (nt stores) +
// P->bf16 via per-wave 1.25KB LDS scratch (80B-padded rows, conflict-free)
// -> PV -> ctx. Zero __syncthreads.
// ---------------------------------------------------------------------------
__global__ __launch_bounds__(256, 4) void attn_kernel(
    const uint16_t* __restrict__ Qhg, const uint16_t* __restrict__ Qlg,
    const uint16_t* __restrict__ Khg, const uint16_t* __restrict__ Klg,
    const uint16_t* __restrict__ Vtg, uint16_t* __restrict__ ctx,
    float* __restrict__ attn_out)
{
  __shared__ __align__(16) uint8_t scratch[4 * 1280];  // per-wave 16 rows x 80B

  // XCD swizzle: 2048 wgs -> 256 consecutive per XCD (16 (b,h) pairs each,
  // so K/V (~768KB per pair) stays L2-resident while its 16 blocks run).
  const int bid = blockIdx.x;
  const int swz = (bid & 7) * 256 + (bid >> 3);
  const int b = swz >> 6, h = (swz >> 4) & 3, q0 = (swz & 15) * 64;

  const int t = threadIdx.x;
  const int w = t >> 6, l = t & 63, lg = l >> 4, l16 = l & 15;
  const int qw = q0 + w * 16;

  const size_t bh = (size_t)(b * 4 + h);
  const uint16_t* Qhp = Qhg + bh * (size_t)(L_ * DH_);
  const uint16_t* Qlp = Qlg + bh * (size_t)(L_ * DH_);
  const uint16_t* Khp = Khg + bh * (size_t)(L_ * DH_);
  const uint16_t* Klp = Klg + bh * (size_t)(L_ * DH_);
  const uint16_t* Vp  = Vtg + bh * (size_t)(DH_ * L_);
  uint8_t* sp = scratch + w * 1280;

  // Q hi fragments: A/B layout [row=l16][k = lg*8+j]
  bf16x8 qfh[4];
  #pragma unroll
  for (int ds = 0; ds < 4; ++ds)
    qfh[ds] = *reinterpret_cast<const bf16x8*>(Qhp + (size_t)(qw + l16) * 128 + ds * 32 + lg * 8);

  // ---- pass 1: rowsum of exp(logits), plain bf16 (sum needs ~1e-3 rel) ----
  float sum = 0.f;
  #pragma unroll 2
  for (int kt = 0; kt < 64; ++kt) {
    bf16x8 kf[4];
    #pragma unroll
    for (int ds = 0; ds < 4; ++ds)
      kf[ds] = *reinterpret_cast<const bf16x8*>(Khp + (size_t)(kt * 16 + l16) * 128 + ds * 32 + lg * 8);
    f32x4 a = {};
    #pragma unroll
    for (int ds = 0; ds < 4; ++ds) a = MFMA16(kf[ds], qfh[ds], a);
    sum += __expf(a[0]) + __expf(a[1]) + __expf(a[2]) + __expf(a[3]);
  }
  sum += __shfl_xor(sum, 16, 64);
  sum += __shfl_xor(sum, 32, 64);
  const float inv = 1.0f / sum;   // valid for lane's q = l16 row

  // ---- pass 2: split-bf16 logits -> attn + PV ----
  bf16x8 qfl[4];
  #pragma unroll
  for (int ds = 0; ds < 4; ++ds)
    qfl[ds] = *reinterpret_cast<const bf16x8*>(Qlp + (size_t)(qw + l16) * 128 + ds * 32 + lg * 8);

  f32x4 cacc[8] = {};
  float* attn_q = attn_out + bh * (size_t)(L_ * L_) + (size_t)(qw + l16) * 1024;

  for (int kp = 0; kp < 32; ++kp) {
    #pragma unroll
    for (int h2 = 0; h2 < 2; ++h2) {
      const int kt = kp * 2 + h2;
      bf16x8 kfh[4], kfl[4];
      #pragma unroll
      for (int ds = 0; ds < 4; ++ds) {
        size_t off = (size_t)(kt * 16 + l16) * 128 + ds * 32 + lg * 8;
        kfh[ds] = *reinterpret_cast<const bf16x8*>(Khp + off);
        kfl[ds] = *reinterpret_cast<const bf16x8*>(Klp + off);
      }
      f32x4 a = {};
      #pragma unroll
      for (int ds = 0; ds < 4; ++ds) {
        a = MFMA16(kfh[ds], qfh[ds], a);
        a = MFMA16(kfh[ds], qfl[ds], a);
        a = MFMA16(kfl[ds], qfh[ds], a);
      }
      f32x4 e;
      #pragma unroll
      for (int r = 0; r < 4; ++r) e[r] = __expf(a[r]) * inv;
      // attn[q=l16 row][k = kt*16 + lg*4 .. +3], nontemporal (don't evict K/V)
      __builtin_nontemporal_store(e, reinterpret_cast<f32x4*>(attn_q + kt * 16 + lg * 4));
      // pack P[q][k] bf16 to per-wave scratch: row q=l16 (80B), col k_local*2
      *reinterpret_cast<uint2*>(sp + l16 * 80 + h2 * 32 + lg * 8) =
          make_uint2(pk2(e[0], e[1]), pk2(e[2], e[3]));
    }
    // A-frag: P[q=l16][k_local = lg*8 .. +7]
    bf16x8 pa = *reinterpret_cast<bf16x8*>(sp + l16 * 80 + lg * 16);
    #pragma unroll
    for (int dt = 0; dt < 8; ++dt) {
      bf16x8 vb = *reinterpret_cast<const bf16x8*>(
          Vp + (size_t)(dt * 16 + l16) * 1024 + kp * 32 + lg * 8);
      cacc[dt] = MFMA16(pa, vb, cacc[dt]);
    }
  }

  // ctx: lane holds ctx[q = lg*4+r][d = dt*16+l16] -> bf16 [b*L+q][h*128+d]
  #pragma unroll
  for (int dt = 0; dt < 8; ++dt) {
    #pragma unroll
    for (int r = 0; r < 4; ++r) {
      size_t row = (size_t)b * 1024 + (size_t)(qw + lg * 4 + r);
      ctx[row * 512 + h * 128 + dt * 16 + l16] = f2bf(cacc[dt][r]);
    }
  }
}

// ---------------------------------------------------------------------------
// Output projection (unchanged from R0 — verified correct).
// ---------------------------------------------------------------------------
__global__ __launch_bounds__(256) void outproj_kernel(
    const uint16_t* __restrict__ ctx, const float* __restrict__ Wf,
    const float* __restrict__ bfp, float* __restrict__ out)
{
  __shared__ __align__(16) uint8_t smem[65536];  // Cs 32KB | Ws 32KB
  uint8_t* Cs = smem;
  uint8_t* Ws = smem + 32768;

  const int t = threadIdx.x;
  const int m0 = blockIdx.x * 64, n0 = blockIdx.y * 64;
  const int w = t >> 6, l = t & 63, lg = l >> 4, l16 = l & 15;
  const int wm = (w >> 1) * 32, wn = (w & 1) * 32;

  f32x4 acc[2][2] = {};

  for (int kc = 0; kc < 2; ++kc) {
    __syncthreads();
    #pragma unroll
    for (int i = 0; i < 8; ++i) {
      int f = i * 256 + t;
      int row = f >> 5, c16 = f & 31;
      bf16x8 v = *reinterpret_cast<const bf16x8*>(ctx + (size_t)(m0 + row) * 512 + kc * 256 + c16 * 8);
      uint32_t byte = ((uint32_t)row * 512 + (uint32_t)c16 * 16) ^ ((uint32_t)(row & 7) << 4);
      *reinterpret_cast<bf16x8*>(Cs + byte) = v;
    }
    #pragma unroll
    for (int i = 0; i < 16; ++i) {
      int f = i * 256 + t;
      int row = f >> 6, c4 = f & 63;
      f32x4 v = *reinterpret_cast<const f32x4*>(Wf + (size_t)(n0 + row) * 512 + kc * 256 + c4 * 4);
      uint32_t byte = ((uint32_t)row * 512 + (uint32_t)c4 * 8) ^ ((uint32_t)(row & 7) << 4);
      uint16_t h0 = f2bf(v[0]), h1 = f2bf(v[1]), h2 = f2bf(v[2]), h3 = f2bf(v[3]);
      *reinterpret_cast<uint2*>(Ws + byte) =
          make_uint2((uint32_t)h0 | ((uint32_t)h1 << 16), (uint32_t)h2 | ((uint32_t)h3 << 16));
    }
    __syncthreads();

    #pragma unroll
    for (int ks = 0; ks < 8; ++ks) {
      bf16x8 a[2], bb[2];
      #pragma unroll
      for (int mt = 0; mt < 2; ++mt) {
        int row = wm + mt * 16 + l16;
        uint32_t byte = ((uint32_t)row * 512 + (uint32_t)(ks * 64 + lg * 16)) ^ ((uint32_t)(row & 7) << 4);
        a[mt] = *reinterpret_cast<bf16x8*>(Cs + byte);
      }
      #pragma unroll
      for (int nt = 0; nt < 2; ++nt) {
        int row = wn + nt * 16 + l16;
        uint32_t byte = ((uint32_t)row * 512 + (uint32_t)(ks * 64 + lg * 16)) ^ ((uint32_t)(row & 7) << 4);
        bb[nt] = *reinterpret_cast<bf16x8*>(Ws + byte);
      }
      #pragma unroll
      for (int mt = 0; mt < 2; ++mt)
        #pragma unroll
        for (int nt = 0; nt < 2; ++nt)
          acc[mt][nt] = MFMA16(a[mt], bb[nt], acc[mt][nt]);
    }
  }

  #pragma unroll
  for (int nt = 0; nt < 2; ++nt) {
    int n = n0 + wn + nt * 16 + l16;
    float bias_v = bfp[n];
    #pragma unroll
    for (int mt = 0; mt < 2; ++mt)
      #pragma unroll
      for (int r = 0; r < 4; ++r) {
        int m = m0 + wm + mt * 16 + lg * 4 + r;
        out[(size_t)m * 256 + n] = acc[mt][nt][r] + bias_v;
      }
  }
}

// ---------------------------------------------------------------------------
extern "C" void kernel_launch(void* const* d_in, const int* in_sizes, int n_in,
                              void* d_out, int out_size, void* d_ws, size_t ws_size,
                              hipStream_t stream) {
  const float* key   = (const float*)d_in[0];
  const float* value = (const float*)d_in[1];
  const float* query = (const float*)d_in[2];
  const float* Wq = (const float*)d_in[3];
  const float* bq = (const float*)d_in[4];
  const float* Wk = (const float*)d_in[5];
  const float* bk = (const float*)d_in[6];
  const float* Wv = (const float*)d_in[7];
  const float* bv = (const float*)d_in[8];
  const float* Wf = (const float*)d_in[9];
  const float* bf = (const float*)d_in[10];

  float* out  = (float*)d_out;
  float* attn = out + (size_t)B_ * L_ * D_;  // out first, then attn (return order)

  const size_t TSZ = (size_t)B_ * H_ * L_ * DH_;  // 16777216 elems
  uint16_t* Qh  = (uint16_t*)d_ws;
  uint16_t* Ql  = Qh + TSZ;
  uint16_t* Kh  = Ql + TSZ;
  uint16_t* Kl  = Kh + TSZ;
  uint16_t* Vt  = Kl + TSZ;
  uint16_t* ctx = Vt + TSZ;  // needs 6*TSZ*2 = 201 MB of ws

  proj_kernel<<<dim3(512, 8, 3), 256, 0, stream>>>(
      query, key, value, Wq, bq, Wk, bk, Wv, bv, Qh, Ql, Kh, Kl, Vt);
  attn_kernel<<<dim3(2048), 256, 0, stream>>>(Qh, Ql, Kh, Kl, Vt, ctx, attn);
  outproj_kernel<<<dim3(512, 4), 256, 0, stream>>>(ctx, Wf, bf, out);
}